// Round 1
// baseline (855.422 us; speedup 1.0000x reference)
//
#include <hip/hip_runtime.h>
#include <hip/hip_bf16.h>
#include <cstdint>

#define CDIM 256
#define KNN  16
#define BM   128
#define BN   128
#define BKK  64

typedef __attribute__((ext_vector_type(8))) __bf16 bf16x8;
typedef __attribute__((ext_vector_type(4))) float  f4;

__device__ inline unsigned short f2bf(float f) {
    unsigned int u = __builtin_bit_cast(unsigned int, f);
    u = (u + 0x7fffu + ((u >> 16) & 1u)) >> 16;
    return (unsigned short)u;
}

// out[M x 256] = A[M x 256] @ W[256 x 256]^T + bias, optionally * sens[row % Npts]
template<int SCALE>
__global__ __launch_bounds__(256, 2)
void proj_gemm(const float* __restrict__ A, const float* __restrict__ W,
               const float* __restrict__ bias, const float* __restrict__ sens,
               float* __restrict__ out, int M, int Npts)
{
    __shared__ unsigned short As[2][BM * BKK];
    __shared__ unsigned short Ws[2][BN * BKK];

    const int tid  = threadIdx.x;
    const int lane = tid & 63;
    const int wid  = tid >> 6;
    const int wr   = wid >> 1, wc = wid & 1;   // 2x2 wave grid, 64x64 per wave
    const int tileM = blockIdx.y * BM;
    const int tileN = blockIdx.x * BN;

    f4 acc[4][4];
    #pragma unroll
    for (int i = 0; i < 4; i++)
        #pragma unroll
        for (int j = 0; j < 4; j++) acc[i][j] = (f4){0.f, 0.f, 0.f, 0.f};

    auto stage = [&](int buf, int k0) {
        #pragma unroll
        for (int i = 0; i < 8; i++) {
            int idx = i * 256 + tid;       // float4 index within 128x64 tile
            int row = idx >> 4;            // 16 float4 per row
            int c4  = idx & 15;
            int grow = tileM + row;
            float4 v = make_float4(0.f, 0.f, 0.f, 0.f);
            if (grow < M) v = *(const float4*)(A + (size_t)grow * CDIM + k0 + c4 * 4);
            ushort4 h;
            h.x = f2bf(v.x); h.y = f2bf(v.y); h.z = f2bf(v.z); h.w = f2bf(v.w);
            int colb = (c4 * 8) ^ ((row & 7) << 4);     // XOR swizzle (G4)
            *(ushort4*)((char*)(&As[buf][0]) + row * 128 + colb) = h;
        }
        #pragma unroll
        for (int i = 0; i < 8; i++) {
            int idx = i * 256 + tid;
            int row = idx >> 4;
            int c4  = idx & 15;
            float4 v = *(const float4*)(W + (size_t)(tileN + row) * CDIM + k0 + c4 * 4);
            ushort4 h;
            h.x = f2bf(v.x); h.y = f2bf(v.y); h.z = f2bf(v.z); h.w = f2bf(v.w);
            int colb = (c4 * 8) ^ ((row & 7) << 4);
            *(ushort4*)((char*)(&Ws[buf][0]) + row * 128 + colb) = h;
        }
    };

    stage(0, 0);
    __syncthreads();

    #pragma unroll
    for (int ks = 0; ks < CDIM / BKK; ++ks) {
        const int buf = ks & 1;
        if (ks + 1 < CDIM / BKK) stage(buf ^ 1, (ks + 1) * BKK);  // prefetch overlaps MFMA
        #pragma unroll
        for (int kk = 0; kk < 2; ++kk) {
            bf16x8 af[4], bfr[4];
            #pragma unroll
            for (int mi = 0; mi < 4; mi++) {
                int row  = wr * 64 + mi * 16 + (lane & 15);
                int colb = (kk * 64 + (lane >> 4) * 16) ^ ((row & 7) << 4);
                af[mi] = *(const bf16x8*)((const char*)(&As[buf][0]) + row * 128 + colb);
            }
            #pragma unroll
            for (int ni = 0; ni < 4; ni++) {
                int row  = wc * 64 + ni * 16 + (lane & 15);
                int colb = (kk * 64 + (lane >> 4) * 16) ^ ((row & 7) << 4);
                bfr[ni] = *(const bf16x8*)((const char*)(&Ws[buf][0]) + row * 128 + colb);
            }
            #pragma unroll
            for (int mi = 0; mi < 4; mi++)
                #pragma unroll
                for (int ni = 0; ni < 4; ni++)
                    acc[mi][ni] = __builtin_amdgcn_mfma_f32_16x16x32_bf16(
                        af[mi], bfr[ni], acc[mi][ni], 0, 0, 0);
        }
        __syncthreads();
    }

    const int r0 = tileM + wr * 64;
    const int c0 = tileN + wc * 64;
    #pragma unroll
    for (int ni = 0; ni < 4; ni++) {
        int col = c0 + ni * 16 + (lane & 15);
        float bc = bias[col];
        #pragma unroll
        for (int mi = 0; mi < 4; mi++) {
            int rbase = r0 + mi * 16 + ((lane >> 4) << 2);   // C/D: col=lane&15, row=(lane>>4)*4+reg
            #pragma unroll
            for (int r = 0; r < 4; r++) {
                int row = rbase + r;
                if (row < M) {
                    float v = acc[mi][ni][r] + bc;
                    if (SCALE) {
                        int n = row >= Npts ? row - Npts : row;
                        v *= sens[n];
                    }
                    out[(size_t)row * CDIM + col] = v;
                }
            }
        }
    }
}

// One wave per point: gathered 16-NN attention + residual + LayerNorm.
// QO holds projected Q on input; overwritten with the final output (each wave
// touches only its own row, so in-place is race-free).
__global__ __launch_bounds__(256, 4)
void attn_ln(float* __restrict__ QO,
             const float* __restrict__ Kt, const float* __restrict__ Vt,
             const int* __restrict__ knn,
             const float* __restrict__ ln_g, const float* __restrict__ ln_b,
             int Ntot, int Npts)
{
    const int w = blockIdx.x * 4 + (threadIdx.x >> 6);
    if (w >= Ntot) return;
    const int lane = threadIdx.x & 63;
    const int row  = w;
    const int n    = row >= Npts ? row - Npts : row;
    const size_t bofs = row >= Npts ? (size_t)Npts * CDIM : 0;

    const float4 q = *(const float4*)(QO + (size_t)row * CDIM + lane * 4);

    int idxs[KNN];
    const int* ki = knn + n * KNN;
    #pragma unroll
    for (int j = 0; j < KNN; j++) idxs[j] = ki[j];

    float d[KNN];
    #pragma unroll
    for (int j = 0; j < KNN; j++) {
        const float4 kv = *(const float4*)(Kt + bofs + (size_t)idxs[j] * CDIM + lane * 4);
        d[j] = q.x * kv.x + q.y * kv.y + q.z * kv.z + q.w * kv.w;
    }
    #pragma unroll
    for (int m = 1; m < 64; m <<= 1) {
        #pragma unroll
        for (int j = 0; j < KNN; j++) d[j] += __shfl_xor(d[j], m, 64);
    }

    float mx = -1e30f;
    #pragma unroll
    for (int j = 0; j < KNN; j++) { d[j] *= 0.0625f; mx = fmaxf(mx, d[j]); }
    float s = 0.f;
    #pragma unroll
    for (int j = 0; j < KNN; j++) { d[j] = __expf(d[j] - mx); s += d[j]; }
    const float inv = 1.f / s;

    float4 o = make_float4(0.f, 0.f, 0.f, 0.f);
    #pragma unroll
    for (int j = 0; j < KNN; j++) {
        const float4 vv = *(const float4*)(Vt + bofs + (size_t)idxs[j] * CDIM + lane * 4);
        const float pj = d[j] * inv;
        o.x += pj * vv.x; o.y += pj * vv.y; o.z += pj * vv.z; o.w += pj * vv.w;
    }

    float4 x;
    x.x = o.x + q.x; x.y = o.y + q.y; x.z = o.z + q.z; x.w = o.w + q.w;

    float ssum = x.x + x.y + x.z + x.w;
    #pragma unroll
    for (int m = 1; m < 64; m <<= 1) ssum += __shfl_xor(ssum, m, 64);
    const float mu = ssum * (1.f / 256.f);

    float4 e;
    e.x = x.x - mu; e.y = x.y - mu; e.z = x.z - mu; e.w = x.w - mu;
    float vsum = e.x * e.x + e.y * e.y + e.z * e.z + e.w * e.w;
    #pragma unroll
    for (int m = 1; m < 64; m <<= 1) vsum += __shfl_xor(vsum, m, 64);
    const float rstd = rsqrtf(vsum * (1.f / 256.f) + 1e-5f);

    const float4 g  = *(const float4*)(ln_g + lane * 4);
    const float4 bb = *(const float4*)(ln_b + lane * 4);
    float4 outv;
    outv.x = e.x * rstd * g.x + bb.x;
    outv.y = e.y * rstd * g.y + bb.y;
    outv.z = e.z * rstd * g.z + bb.z;
    outv.w = e.w * rstd * g.w + bb.w;
    *(float4*)(QO + (size_t)row * CDIM + lane * 4) = outv;
}

extern "C" void kernel_launch(void* const* d_in, const int* in_sizes, int n_in,
                              void* d_out, int out_size, void* d_ws, size_t ws_size,
                              hipStream_t stream)
{
    const float* q_feat  = (const float*)d_in[0];
    const float* kv_feat = (const float*)d_in[1];
    const int*   knn     = (const int*)d_in[2];
    const float* sens    = (const float*)d_in[3];
    const float* Wq_w    = (const float*)d_in[4];
    const float* Wq_b    = (const float*)d_in[5];
    const float* Wk_w    = (const float*)d_in[6];
    const float* Wk_b    = (const float*)d_in[7];
    const float* Wv_w    = (const float*)d_in[8];
    const float* Wv_b    = (const float*)d_in[9];
    const float* ln_g    = (const float*)d_in[10];
    const float* ln_b    = (const float*)d_in[11];

    const int Npts = in_sizes[3];          // N = 50000
    const int M    = in_sizes[0] / CDIM;   // B*N = 100000

    float* Q  = (float*)d_out;             // Q lives in d_out, overwritten by attn_ln
    float* Kt = (float*)d_ws;
    float* Vt = Kt + (size_t)M * CDIM;

    dim3 grid(CDIM / BN, (M + BM - 1) / BM);
    dim3 blk(256);
    proj_gemm<0><<<grid, blk, 0, stream>>>(q_feat,  Wq_w, Wq_b, nullptr, Q,  M, Npts);
    proj_gemm<1><<<grid, blk, 0, stream>>>(kv_feat, Wk_w, Wk_b, sens,    Kt, M, Npts);
    proj_gemm<1><<<grid, blk, 0, stream>>>(kv_feat, Wv_w, Wv_b, sens,    Vt, M, Npts);

    const int nblk = (M + 3) / 4;          // 4 waves per block, 1 point per wave
    attn_ln<<<nblk, blk, 0, stream>>>(Q, Kt, Vt, knn, ln_g, ln_b, M, Npts);
}

// Round 2
// 504.657 us; speedup vs baseline: 1.6951x; 1.6951x over previous
//
#include <hip/hip_runtime.h>
#include <hip/hip_bf16.h>
#include <cstdint>

#define CDIM 256
#define KNN  16
#define BM   128
#define BN   128
#define BKK  64

typedef __attribute__((ext_vector_type(8))) __bf16 bf16x8;
typedef __attribute__((ext_vector_type(4))) float  f4;

__device__ inline unsigned short f2bf(float f) {
    unsigned int u = __builtin_bit_cast(unsigned int, f);
    u = (u + 0x7fffu + ((u >> 16) & 1u)) >> 16;
    return (unsigned short)u;
}
__device__ inline float bf2f(unsigned short h) {
    return __builtin_bit_cast(float, (unsigned int)h << 16);
}
__device__ inline void gld16(const void* src, void* dst) {
    __builtin_amdgcn_global_load_lds(
        (const __attribute__((address_space(1))) void*)src,
        (__attribute__((address_space(3))) void*)dst, 16, 0, 0);
}

// One-shot f32 -> bf16 conversion of q_feat, kv_feat, and the three weight mats.
__global__ __launch_bounds__(256)
void conv_bf16(const float* __restrict__ q, const float* __restrict__ kv,
               const float* __restrict__ Wq, const float* __restrict__ Wk,
               const float* __restrict__ Wv,
               ushort* __restrict__ qb, ushort* __restrict__ kvb,
               ushort* __restrict__ wb, int n4feat, int n4w)
{
    const int i0 = blockIdx.x * blockDim.x + threadIdx.x;
    const int stride = gridDim.x * blockDim.x;
    for (int i = i0; i < n4feat; i += stride) {
        float4 a = ((const float4*)q)[i];
        ushort4 h;
        h.x = f2bf(a.x); h.y = f2bf(a.y); h.z = f2bf(a.z); h.w = f2bf(a.w);
        ((ushort4*)qb)[i] = h;
        float4 b = ((const float4*)kv)[i];
        h.x = f2bf(b.x); h.y = f2bf(b.y); h.z = f2bf(b.z); h.w = f2bf(b.w);
        ((ushort4*)kvb)[i] = h;
    }
    if (i0 < n4w) {
        const int wsel = i0 / (65536 / 4);
        const int off  = i0 - wsel * (65536 / 4);
        const float* Wp = wsel == 0 ? Wq : (wsel == 1 ? Wk : Wv);
        float4 a = ((const float4*)Wp)[off];
        ushort4 h;
        h.x = f2bf(a.x); h.y = f2bf(a.y); h.z = f2bf(a.z); h.w = f2bf(a.w);
        ((ushort4*)(wb + wsel * 65536))[off] = h;
    }
}

// out[M x 256] = A[M x 256] @ W[256 x 256]^T + bias (OUTMODE 1: * sens, bf16 out)
// A, W already bf16. global_load_lds staging: linear LDS dest, inverse-swizzled
// per-lane global source, swizzled ds_read (rule 21).
template<int OUTMODE>
__global__ __launch_bounds__(256, 2)
void proj_gemm_bf(const ushort* __restrict__ A, const ushort* __restrict__ W,
                  const float* __restrict__ bias, const float* __restrict__ sens,
                  void* __restrict__ outp, int M, int Npts)
{
    __shared__ ushort As[2][BM * BKK];
    __shared__ ushort Ws[2][BN * BKK];

    const int tid  = threadIdx.x;
    const int lane = tid & 63;
    const int wid  = tid >> 6;
    const int wr   = wid >> 1, wc = wid & 1;   // 2x2 wave grid, 64x64 per wave
    const int tileM = blockIdx.y * BM;
    const int tileN = blockIdx.x * BN;

    f4 acc[4][4];
    #pragma unroll
    for (int i = 0; i < 4; i++)
        #pragma unroll
        for (int j = 0; j < 4; j++) acc[i][j] = (f4){0.f, 0.f, 0.f, 0.f};

    // each wave stages 32 rows of each tile: 4 calls x (64 lanes x 16B = 8 rows)
    const int rbaseS = wid * 32 + (lane >> 3);
    const int cbS    = ((lane & 7) * 16) ^ ((lane >> 3) << 4);  // inverse-swizzled src col-byte
    auto stage = [&](int buf, int k0) {
        #pragma unroll
        for (int i = 0; i < 4; i++) {
            const int rr = rbaseS + i * 8;
            gld16((const char*)(A + (size_t)(tileM + rr) * CDIM + k0) + cbS,
                  (char*)(&As[buf][0]) + wid * 4096 + i * 1024);
            gld16((const char*)(W + (size_t)(tileN + rr) * CDIM + k0) + cbS,
                  (char*)(&Ws[buf][0]) + wid * 4096 + i * 1024);
        }
    };

    stage(0, 0);
    __syncthreads();

    #pragma unroll
    for (int ks = 0; ks < CDIM / BKK; ++ks) {
        const int buf = ks & 1;
        if (ks + 1 < CDIM / BKK) stage(buf ^ 1, (ks + 1) * BKK);
        #pragma unroll
        for (int kk = 0; kk < 2; ++kk) {
            bf16x8 af[4], bfr[4];
            #pragma unroll
            for (int mi = 0; mi < 4; mi++) {
                int row  = wr * 64 + mi * 16 + (lane & 15);
                int colb = (kk * 64 + (lane >> 4) * 16) ^ ((row & 7) << 4);
                af[mi] = *(const bf16x8*)((const char*)(&As[buf][0]) + row * 128 + colb);
            }
            #pragma unroll
            for (int ni = 0; ni < 4; ni++) {
                int row  = wc * 64 + ni * 16 + (lane & 15);
                int colb = (kk * 64 + (lane >> 4) * 16) ^ ((row & 7) << 4);
                bfr[ni] = *(const bf16x8*)((const char*)(&Ws[buf][0]) + row * 128 + colb);
            }
            #pragma unroll
            for (int mi = 0; mi < 4; mi++)
                #pragma unroll
                for (int ni = 0; ni < 4; ni++)
                    acc[mi][ni] = __builtin_amdgcn_mfma_f32_16x16x32_bf16(
                        af[mi], bfr[ni], acc[mi][ni], 0, 0, 0);
        }
        __syncthreads();
    }

    const int r0 = tileM + wr * 64;
    const int c0 = tileN + wc * 64;
    #pragma unroll
    for (int ni = 0; ni < 4; ni++) {
        int col = c0 + ni * 16 + (lane & 15);
        float bc = bias[col];
        #pragma unroll
        for (int mi = 0; mi < 4; mi++) {
            int rbase = r0 + mi * 16 + ((lane >> 4) << 2);   // C/D: col=lane&15, row=(lane>>4)*4+reg
            #pragma unroll
            for (int r = 0; r < 4; r++) {
                int row = rbase + r;
                if (row < M) {
                    float v = acc[mi][ni][r] + bc;
                    if (OUTMODE) {
                        int n = row >= Npts ? row - Npts : row;
                        ((ushort*)outp)[(size_t)row * CDIM + col] = f2bf(v * sens[n]);
                    } else {
                        ((float*)outp)[(size_t)row * CDIM + col] = v;
                    }
                }
            }
        }
    }
}

// One wave per point: gathered 16-NN attention (bf16 K/V) + residual + LayerNorm.
__global__ __launch_bounds__(256, 4)
void attn_ln_bf(float* __restrict__ QO,
                const ushort* __restrict__ Kt, const ushort* __restrict__ Vt,
                const int* __restrict__ knn,
                const float* __restrict__ ln_g, const float* __restrict__ ln_b,
                int Ntot, int Npts)
{
    const int w = blockIdx.x * 4 + (threadIdx.x >> 6);
    if (w >= Ntot) return;
    const int lane = threadIdx.x & 63;
    const int n    = w >= Npts ? w - Npts : w;
    const size_t bofs = w >= Npts ? (size_t)Npts * CDIM : 0;

    const float4 q = *(const float4*)(QO + (size_t)w * CDIM + lane * 4);

    int idxs[KNN];
    const int* ki = knn + n * KNN;
    #pragma unroll
    for (int j = 0; j < KNN; j++) idxs[j] = ki[j];

    float d[KNN];
    #pragma unroll
    for (int j = 0; j < KNN; j++) {
        ushort4 kv = *(const ushort4*)(Kt + bofs + (size_t)idxs[j] * CDIM + lane * 4);
        d[j] = q.x * bf2f(kv.x) + q.y * bf2f(kv.y) + q.z * bf2f(kv.z) + q.w * bf2f(kv.w);
    }
    // hoist V gathers so HBM latency hides under the reduce/softmax
    ushort4 vr[KNN];
    #pragma unroll
    for (int j = 0; j < KNN; j++)
        vr[j] = *(const ushort4*)(Vt + bofs + (size_t)idxs[j] * CDIM + lane * 4);

    #pragma unroll
    for (int m = 1; m < 64; m <<= 1) {
        #pragma unroll
        for (int j = 0; j < KNN; j++) d[j] += __shfl_xor(d[j], m, 64);
    }

    float mx = -1e30f;
    #pragma unroll
    for (int j = 0; j < KNN; j++) { d[j] *= 0.0625f; mx = fmaxf(mx, d[j]); }
    float s = 0.f;
    #pragma unroll
    for (int j = 0; j < KNN; j++) { d[j] = __expf(d[j] - mx); s += d[j]; }
    const float inv = 1.f / s;

    float4 o = make_float4(0.f, 0.f, 0.f, 0.f);
    #pragma unroll
    for (int j = 0; j < KNN; j++) {
        const float pj = d[j] * inv;
        o.x += pj * bf2f(vr[j].x); o.y += pj * bf2f(vr[j].y);
        o.z += pj * bf2f(vr[j].z); o.w += pj * bf2f(vr[j].w);
    }

    float4 x;
    x.x = o.x + q.x; x.y = o.y + q.y; x.z = o.z + q.z; x.w = o.w + q.w;

    float ssum = x.x + x.y + x.z + x.w;
    #pragma unroll
    for (int m = 1; m < 64; m <<= 1) ssum += __shfl_xor(ssum, m, 64);
    const float mu = ssum * (1.f / 256.f);

    float4 e;
    e.x = x.x - mu; e.y = x.y - mu; e.z = x.z - mu; e.w = x.w - mu;
    float vsum = e.x * e.x + e.y * e.y + e.z * e.z + e.w * e.w;
    #pragma unroll
    for (int m = 1; m < 64; m <<= 1) vsum += __shfl_xor(vsum, m, 64);
    const float rstd = rsqrtf(vsum * (1.f / 256.f) + 1e-5f);

    const float4 g  = *(const float4*)(ln_g + lane * 4);
    const float4 bb = *(const float4*)(ln_b + lane * 4);
    float4 outv;
    outv.x = e.x * rstd * g.x + bb.x;
    outv.y = e.y * rstd * g.y + bb.y;
    outv.z = e.z * rstd * g.z + bb.z;
    outv.w = e.w * rstd * g.w + bb.w;
    *(float4*)(QO + (size_t)w * CDIM + lane * 4) = outv;
}

extern "C" void kernel_launch(void* const* d_in, const int* in_sizes, int n_in,
                              void* d_out, int out_size, void* d_ws, size_t ws_size,
                              hipStream_t stream)
{
    const float* q_feat  = (const float*)d_in[0];
    const float* kv_feat = (const float*)d_in[1];
    const int*   knn     = (const int*)d_in[2];
    const float* sens    = (const float*)d_in[3];
    const float* Wq_w    = (const float*)d_in[4];
    const float* Wq_b    = (const float*)d_in[5];
    const float* Wk_w    = (const float*)d_in[6];
    const float* Wk_b    = (const float*)d_in[7];
    const float* Wv_w    = (const float*)d_in[8];
    const float* Wv_b    = (const float*)d_in[9];
    const float* ln_g    = (const float*)d_in[10];
    const float* ln_b    = (const float*)d_in[11];

    const int Npts = in_sizes[3];              // N = 50000
    const int M    = in_sizes[0] / CDIM;       // B*N = 100000
    const int Mpad = ((M + BM - 1) / BM) * BM; // padded so GEMM staging never branches

    // ws layout (3 * Mpad*C bf16 + weights ~= 154 MB):
    //   [Qbf (reused as Ktb)] [KVbf] [Vtb] [Wb x3]
    // Ktb aliasing Qbf is safe: same-stream ordering means gemm-Q has finished
    // reading Qbf before gemm-K writes Ktb.
    ushort* Qbf  = (ushort*)d_ws;
    ushort* KVbf = Qbf  + (size_t)Mpad * CDIM;
    ushort* Vtb  = KVbf + (size_t)Mpad * CDIM;
    ushort* Wb   = Vtb  + (size_t)Mpad * CDIM;
    ushort* Ktb  = Qbf;

    conv_bf16<<<2048, 256, 0, stream>>>(q_feat, kv_feat, Wq_w, Wk_w, Wv_w,
                                        Qbf, KVbf, Wb,
                                        M * CDIM / 4, 3 * 65536 / 4);

    dim3 grid(CDIM / BN, Mpad / BM);
    dim3 blk(256);
    proj_gemm_bf<0><<<grid, blk, 0, stream>>>(Qbf,  Wb,          Wq_b, nullptr, d_out, M, Npts);
    proj_gemm_bf<1><<<grid, blk, 0, stream>>>(KVbf, Wb + 65536,  Wk_b, sens,    Ktb,   M, Npts);
    proj_gemm_bf<1><<<grid, blk, 0, stream>>>(KVbf, Wb + 131072, Wv_b, sens,    Vtb,   M, Npts);

    attn_ln_bf<<<(M + 3) / 4, blk, 0, stream>>>((float*)d_out, Ktb, Vtb, knn,
                                                ln_g, ln_b, M, Npts);
}